// Round 8
// baseline (393.097 us; speedup 1.0000x reference)
//
#include <hip/hip_runtime.h>

typedef __attribute__((ext_vector_type(8))) short bf16x8;
typedef __attribute__((ext_vector_type(4))) float f32x4;

__device__ __forceinline__ float b2f(unsigned short u) {
    union { unsigned int i; float f; } x; x.i = ((unsigned int)u) << 16; return x.f;
}
__device__ __forceinline__ unsigned short f2b(float f) {
    union { float f; unsigned int i; } x; x.f = f;
    unsigned int r = x.i + 0x7fffu + ((x.i >> 16) & 1u);  // RNE
    return (unsigned short)(r >> 16);
}

// async global->LDS, 16 B per lane (wave-uniform LDS base + lane*16 layout)
__device__ __forceinline__ void gl16(unsigned short* l, const unsigned short* g) {
    __builtin_amdgcn_global_load_lds((__attribute__((address_space(1))) void*)g,
                                     (__attribute__((address_space(3))) void*)l, 16, 0, 0);
}

// Partial Cox-de Boor exactly as the reference leaves it:
// cols 0-4 degree 3, col 5 degree 2, col 6 degree 1, col 7 degree 0.
// knots = [-1,-1,-1,-1,-0.6,-0.2,0.2,0.6,1,1,1,1]
__device__ __forceinline__ float kan_spline(float t, const float* cpf, float rwf) {
    float c3 = (t >= -1.0f && t < -0.6f) ? 1.0f : 0.0f;
    float c4 = (t >= -0.6f && t < -0.2f) ? 1.0f : 0.0f;
    float c5 = (t >= -0.2f && t <  0.2f) ? 1.0f : 0.0f;
    float c6 = (t >=  0.2f && t <  0.6f) ? 1.0f : 0.0f;
    float c7 = (t >=  0.6f && t <  1.0f) ? 1.0f : 0.0f;
    float d2 = (-0.6f - t) * 2.5f * c3;
    float d3 = (t + 1.0f) * 2.5f * c3 + (-0.2f - t) * 2.5f * c4;
    float d4 = (t + 0.6f) * 2.5f * c4 + ( 0.2f - t) * 2.5f * c5;
    float d5 = (t + 0.2f) * 2.5f * c5 + ( 0.6f - t) * 2.5f * c6;
    float d6 = (t - 0.2f) * 2.5f * c6 + ( 1.0f - t) * 2.5f * c7;
    float e1 = (-0.6f - t) * 2.5f  * d2;
    float e2 = (t + 1.0f) * 2.5f  * d2 + (-0.2f - t) * 1.25f * d3;
    float e3 = (t + 1.0f) * 1.25f * d3 + ( 0.2f - t) * 1.25f * d4;
    float e4 = (t + 0.6f) * 1.25f * d4 + ( 0.6f - t) * 1.25f * d5;
    float e5 = (t + 0.2f) * 1.25f * d5 + ( 1.0f - t) * 1.25f * d6;
    const float r12 = 1.0f / 1.2f;
    float f0 = (-0.6f - t) * 2.5f  * e1;
    float f1 = (t + 1.0f) * 2.5f  * e1 + (-0.2f - t) * 1.25f * e2;
    float f2 = (t + 1.0f) * 1.25f * e2 + ( 0.2f - t) * r12   * e3;
    float f3 = (t + 1.0f) * r12   * e3 + ( 0.6f - t) * r12   * e4;
    float f4 = (t + 0.6f) * r12   * e4 + ( 1.0f - t) * r12   * e5;
    float sp = f0*cpf[0] + f1*cpf[1] + f2*cpf[2] + f3*cpf[3] + f4*cpf[4]
             + e5*cpf[5] + d6*cpf[6] + c7*cpf[7];
    float v = sp * rwf;
    return fminf(fmaxf(v, -10.0f), 10.0f);
}

// per-row mean / rstd of x[1024,2048] f32, fp64 accumulate (fallback paths)
__global__ void ln_stats_kernel(const float* __restrict__ x,
                                float* __restrict__ mu, float* __restrict__ rstd) {
    const int row = blockIdx.x;
    const float* p = x + (size_t)row * 2048 + threadIdx.x * 8;
    double s = 0.0, q = 0.0;
#pragma unroll
    for (int i = 0; i < 8; ++i) { float v = p[i]; s += v; q += (double)v * v; }
    for (int o = 32; o > 0; o >>= 1) { s += __shfl_down(s, o, 64); q += __shfl_down(q, o, 64); }
    __shared__ double shs[4], shq[4];
    const int lane = threadIdx.x & 63, w = threadIdx.x >> 6;
    if (lane == 0) { shs[w] = s; shq[w] = q; }
    __syncthreads();
    if (threadIdx.x == 0) {
        double S = shs[0] + shs[1] + shs[2] + shs[3];
        double Q = shq[0] + shq[1] + shq[2] + shq[3];
        double m = S / 2048.0;
        double var = Q / 2048.0 - m * m;
        mu[row] = (float)m;
        rstd[row] = (float)(1.0 / sqrt(var + 1e-5));
    }
}

// S[n] = sum_k W[n,k] (f32 W); one wave per row, 4 rows per block (fallback)
__global__ void rowsum_kernel(const float* __restrict__ W,
                              float* __restrict__ S, int K) {
    const int lane = threadIdx.x & 63, w = threadIdx.x >> 6;
    const int row = blockIdx.x * 4 + w;
    const float* p = W + (size_t)row * K;
    double s = 0.0;
    for (int c = lane * 8; c < K; c += 512) {
#pragma unroll
        for (int i = 0; i < 8; ++i) s += p[c + i];
    }
    for (int o = 32; o > 0; o >>= 1) s += __shfl_down(s, o, 64);
    if (lane == 0) S[row] = (float)s;
}

// [R,C] f32 -> [R,2C] bf16 as [hi | lo]; one block per row, C = 2048 (fallback)
__global__ void split2_kernel(const float* __restrict__ src,
                              unsigned short* __restrict__ dst, int C) {
    const int r = blockIdx.x;
    const int c = threadIdx.x * 8;
    const float* p = src + (size_t)r * C + c;
    float4 u0 = ((const float4*)p)[0];
    float4 u1 = ((const float4*)p)[1];
    float v[8] = {u0.x, u0.y, u0.z, u0.w, u1.x, u1.y, u1.z, u1.w};
    unsigned short hi[8], lo[8];
#pragma unroll
    for (int i = 0; i < 8; ++i) {
        hi[i] = f2b(v[i]);
        lo[i] = f2b(v[i] - b2f(hi[i]));
    }
    unsigned short* d = dst + (size_t)r * 2 * C + c;
    *(uint4*)d = *(const uint4*)hi;
    *(uint4*)(d + C) = *(const uint4*)lo;
}

// ============================================================================
// pre_all: fused preprocessing, ONE launch (round-7 proven).
// blocks [0,1024):    x row r -> LN stats + hi|lo split into Asplit.
// blocks [1024,5120): W1 row r -> row sum (fp64) into S1 + hi|lo split -> W1b.
// ============================================================================
__global__ void pre_all(const float* __restrict__ x, const float* __restrict__ W1,
                        float* __restrict__ mu, float* __restrict__ rstd,
                        float* __restrict__ S1,
                        unsigned short* __restrict__ Asplit,
                        unsigned short* __restrict__ W1b) {
    const int tid = threadIdx.x;
    const int lane = tid & 63, w = tid >> 6;
    const int c = tid * 8;
    __shared__ double shs[4], shq[4];
    if (blockIdx.x < 1024) {
        const int r = blockIdx.x;
        const float* p = x + (size_t)r * 2048 + c;
        float4 u0 = ((const float4*)p)[0];
        float4 u1 = ((const float4*)p)[1];
        float v[8] = {u0.x, u0.y, u0.z, u0.w, u1.x, u1.y, u1.z, u1.w};
        double s = 0.0, q = 0.0;
#pragma unroll
        for (int i = 0; i < 8; ++i) { s += v[i]; q += (double)v[i] * v[i]; }
        for (int o = 32; o > 0; o >>= 1) { s += __shfl_down(s, o, 64); q += __shfl_down(q, o, 64); }
        if (lane == 0) { shs[w] = s; shq[w] = q; }
        __syncthreads();
        if (tid == 0) {
            double S = shs[0] + shs[1] + shs[2] + shs[3];
            double Q = shq[0] + shq[1] + shq[2] + shq[3];
            double m = S / 2048.0;
            double var = Q / 2048.0 - m * m;
            mu[r] = (float)m;
            rstd[r] = (float)(1.0 / sqrt(var + 1e-5));
        }
        unsigned short hi[8], lo[8];
#pragma unroll
        for (int i = 0; i < 8; ++i) {
            hi[i] = f2b(v[i]);
            lo[i] = f2b(v[i] - b2f(hi[i]));
        }
        unsigned short* d = Asplit + (size_t)r * 4096 + c;
        *(uint4*)d = *(const uint4*)hi;
        *(uint4*)(d + 2048) = *(const uint4*)lo;
    } else {
        const int r = blockIdx.x - 1024;
        const float* p = W1 + (size_t)r * 2048 + c;
        float4 u0 = ((const float4*)p)[0];
        float4 u1 = ((const float4*)p)[1];
        float v[8] = {u0.x, u0.y, u0.z, u0.w, u1.x, u1.y, u1.z, u1.w};
        double s = 0.0;
#pragma unroll
        for (int i = 0; i < 8; ++i) s += v[i];
        for (int o = 32; o > 0; o >>= 1) s += __shfl_down(s, o, 64);
        if (lane == 0) shs[w] = s;
        __syncthreads();
        if (tid == 0) S1[r] = (float)(shs[0] + shs[1] + shs[2] + shs[3]);
        unsigned short hi[8], lo[8];
#pragma unroll
        for (int i = 0; i < 8; ++i) {
            hi[i] = f2b(v[i]);
            lo[i] = f2b(v[i] - b2f(hi[i]));
        }
        unsigned short* d = W1b + (size_t)r * 4096 + c;
        *(uint4*)d = *(const uint4*)hi;
        *(uint4*)(d + 2048) = *(const uint4*)lo;
    }
}

// flat f32 -> bf16, 8 el/thread
__global__ void cvt_kernel(const float* __restrict__ src,
                           unsigned short* __restrict__ dst) {
    const size_t i = ((size_t)blockIdx.x * 256 + threadIdx.x) * 8;
    float4 u0 = ((const float4*)(src + i))[0];
    float4 u1 = ((const float4*)(src + i))[1];
    float v[8] = {u0.x, u0.y, u0.z, u0.w, u1.x, u1.y, u1.z, u1.w};
    unsigned short t[8];
#pragma unroll
    for (int q = 0; q < 8; ++q) t[q] = f2b(v[q]);
    *(uint4*)(dst + i) = *(const uint4*)t;
}

// two-range flat f32 -> bf16 in one launch (W3 + Wout): kills one launch.
__global__ void cvt2_kernel(const float* __restrict__ s1, unsigned short* __restrict__ d1,
                            int nb1, const float* __restrict__ s2,
                            unsigned short* __restrict__ d2) {
    const int b = blockIdx.x;
    const float* src = (b < nb1) ? s1 : s2;
    unsigned short* dst = (b < nb1) ? d1 : d2;
    const int bb = (b < nb1) ? b : b - nb1;
    const size_t i = ((size_t)bb * 256 + threadIdx.x) * 8;
    float4 u0 = ((const float4*)(src + i))[0];
    float4 u1 = ((const float4*)(src + i))[1];
    float v[8] = {u0.x, u0.y, u0.z, u0.w, u1.x, u1.y, u1.z, u1.w};
    unsigned short t[8];
#pragma unroll
    for (int q = 0; q < 8; ++q) t[q] = f2b(v[q]);
    *(uint4*)(dst + i) = *(const uint4*)t;
}

// split-K reducer: v = P0[m][n] + P1[m][n] + bias, then epilogue.
// RK 1: KAN+NCT, bf16 out. RK 2: f32 out. grid = 1024 rows x 256 thr x 8 col.
// (validated numerically in round 5; two-pointer form avoids buffer overlap)
template <int RK>
__global__ void reduce_epi(const float* __restrict__ P0, const float* __restrict__ P1,
                           const float* __restrict__ bias,
                           const float* __restrict__ cp, const float* __restrict__ rw,
                           void* __restrict__ outp, int N) {
    const int m = blockIdx.x;
    const int c0 = threadIdx.x * 8;
    const float* p0 = P0 + (size_t)m * N + c0;
    const float* p1 = P1 + (size_t)m * N + c0;
    float4 a0 = ((const float4*)p0)[0], a1 = ((const float4*)p0)[1];
    float4 b0 = ((const float4*)p1)[0], b1 = ((const float4*)p1)[1];
    float v[8] = {a0.x + b0.x, a0.y + b0.y, a0.z + b0.z, a0.w + b0.w,
                  a1.x + b1.x, a1.y + b1.y, a1.z + b1.z, a1.w + b1.w};
#pragma unroll
    for (int i = 0; i < 8; ++i) v[i] += bias[c0 + i];
    if constexpr (RK == 1) {
        float w[8];
#pragma unroll
        for (int i = 0; i < 8; ++i) {
            const int n = c0 + i;
            float cpf[8];
#pragma unroll
            for (int q = 0; q < 8; ++q) cpf[q] = cp[(size_t)n * 9 + q];
            w[i] = kan_spline(tanhf(v[i]), cpf, rw[n]);
        }
        unsigned short o[8];
#pragma unroll
        for (int i = 0; i < 8; ++i) {
            float val = w[i];
            const int s = i;                 // c0 % 8 == 0, so (c0+i)&7 == i
            float p = fminf(fmaxf(w[i ^ 1], -1.0f), 1.0f);
            if (s < 4) val += ((s == 2) ? -0.05f : 0.05f) * p;
            o[i] = f2b(val);
        }
        *(uint4*)((unsigned short*)outp + (size_t)m * N + c0) = *(const uint4*)o;
    } else {
        float* o = (float*)outp + (size_t)m * N + c0;
        ((float4*)o)[0] = make_float4(v[0], v[1], v[2], v[3]);
        ((float4*)o)[1] = make_float4(v[4], v[5], v[6], v[7]);
    }
}

// ============================================================================
// gemm_kan2: ROUND-3 EXACT core (measured 79.9 us L1, reproduced twice) +
// optional split-K addressing (kh from grid y, koff = kh*Ktot).
// C[1024 x Ncols] = A @ B^T, bf16 inputs, fused LN-fold/KAN/NCT.
// BM=64 BN=128 BK=64, 4 waves 2x2 (wave tile 32x64, acc[2][4]); 512-block
// grids = 2 blocks/CU (proven vs 1 block/CU latency-bound, rounds 4+6).
// Triple-buffered LDS (72 KB), 2-deep global_load_lds prefetch, ONE raw
// s_barrier per K-step preceded by COUNTED s_waitcnt vmcnt(6). sched_barrier
// pins ds_reads below the barrier. XOR bank-conflict swizzle source+read
// side, LDS dest linear (measured 0 conflicts). XCD-chunked grid swizzle.
// EPI 0: lin = rstd*(acc - mu*S1) + bias, KAN+NCT, bf16 out (L1, Ktot=6144
//        mapped: seg0 hi*hi, seg1 lo*hi, seg2 hi*lo over [xhi|xlo]/[Whi|Wlo]).
// EPI 1: acc+bias, KAN+NCT, bf16.  EPI 2: acc+bias, f32.
// EPI 3: raw f32 partial at P[kh*khoff + m*Nld + n] (split-K, no epilogue).
// ============================================================================
template <int EPI>
__global__ __launch_bounds__(256, 2)
void gemm_kan2(const unsigned short* __restrict__ Ab,
               const unsigned short* __restrict__ Bb,
               const float* __restrict__ bias, const float* __restrict__ cp,
               const float* __restrict__ rw, const float* __restrict__ mu,
               const float* __restrict__ rstd, const float* __restrict__ S1,
               void* __restrict__ outp,
               int Nld, int n0, int Ktot, int lda, int ldb, int nbn, int khoff)
{
    constexpr int BM = 64, BN = 128, BK = 64;
    constexpr int ASZ = BM * BK;        // 4096 shorts = 8 KB
    constexpr int BUF = ASZ + BN * BK;  // 12288 shorts = 24 KB
    __shared__ unsigned short lds[3 * BUF];  // 72 KB triple buffer

    const int tid  = threadIdx.x;
    const int lane = tid & 63;
    const int wid  = tid >> 6;

    // XCD-chunked bijective swizzle (nwg % 8 == 0 for every launch here)
    const int gx = gridDim.x;
    int flat = blockIdx.y * gx + blockIdx.x;
    const int nwg = gx * gridDim.y;
    if ((nwg & 7) == 0) flat = (flat & 7) * (nwg >> 3) + (flat >> 3);
    const int bm = (flat % gx) * BM;
    const int rest = flat / gx;
    const int bn = (rest % nbn) * BN;
    const int kh = rest / nbn;              // split-K half (0 when nbn == gridDim.y)
    const int koff = kh * Ktot;

    const int wmo = (wid >> 1) * 32;   // wave row offset within BM
    const int wno = (wid & 1) * 64;    // wave col offset within BN
    const int fr = lane & 15;
    const int kq = lane >> 4;
    const int sxr = fr & 7;            // read-side XOR term (row & 7)

    // staging unit u: LDS linear dest = u*16B (row u>>3, 16B-slot u&7);
    // global source slot = (u&7) ^ (row&7)   [inverse swizzle on source]
    const int uA0 = (wid << 7) + lane;          // A: 512 units, 2 per thread
    const int uA1 = uA0 + 64;
    const int uB0 = (wid << 8) + lane;          // B: 1024 units, 4 per thread
    const int uB1 = uB0 + 64, uB2 = uB0 + 128, uB3 = uB0 + 192;
#define SRCOL(u) (((((u) & 7) ^ (((u) >> 3) & 7))) << 3)
    const size_t aoff0 = (size_t)(bm + (uA0 >> 3)) * lda + SRCOL(uA0) + koff;
    const size_t aoff1 = (size_t)(bm + (uA1 >> 3)) * lda + SRCOL(uA1) + koff;
    const size_t boff0 = (size_t)(bn + (uB0 >> 3)) * ldb + SRCOL(uB0) + koff;
    const size_t boff1 = (size_t)(bn + (uB1 >> 3)) * ldb + SRCOL(uB1) + koff;
    const size_t boff2 = (size_t)(bn + (uB2 >> 3)) * ldb + SRCOL(uB2) + koff;
    const size_t boff3 = (size_t)(bn + (uB3 >> 3)) * ldb + SRCOL(uB3) + koff;
#undef SRCOL

    f32x4 acc[2][4] = {};

#define STAGE(BSEL, AK, BKK) do {                                     \
    unsigned short* lA_ = &lds[(BSEL) * BUF];                         \
    unsigned short* lB_ = lA_ + ASZ;                                  \
    gl16(lA_ + uA0 * 8, Ab + aoff0 + (AK));                           \
    gl16(lA_ + uA1 * 8, Ab + aoff1 + (AK));                           \
    gl16(lB_ + uB0 * 8, Bb + boff0 + (BKK));                          \
    gl16(lB_ + uB1 * 8, Bb + boff1 + (BKK));                          \
    gl16(lB_ + uB2 * 8, Bb + boff2 + (BKK));                          \
    gl16(lB_ + uB3 * 8, Bb + boff3 + (BKK));                          \
} while (0)

    const int nt = Ktot / BK;
    STAGE(0, 0, 0);
    STAGE(1, BK, BK);   // kn=64 < 2048: no segment remap needed at any EPI

    for (int t = 0; t < nt; ++t) {
        // counted drain: allow the (t+1)-tile STAGE (6 loads) to stay in
        // flight across the barrier; own t-tile loads are then complete.
        if (t + 1 < nt) asm volatile("s_waitcnt vmcnt(6)" ::: "memory");
        else            asm volatile("s_waitcnt vmcnt(0)" ::: "memory");
        __builtin_amdgcn_s_barrier();
        __builtin_amdgcn_sched_barrier(0);  // pin ds_reads below the barrier
        if (t + 2 < nt) {
            const int kn = (t + 2) * BK;
            int ak = kn, bk = kn;
            if (EPI == 0) {
                ak = (kn < 4096) ? kn : kn - 4096;
                bk = (kn < 2048) ? kn : kn - 2048;
            }
            STAGE((t + 2) % 3, ak, bk);
        }
        const unsigned short* cl = &lds[(t % 3) * BUF];
#pragma unroll
        for (int s = 0; s < 2; ++s) {
            const int sl = ((((s << 2) + kq) ^ sxr)) << 3;  // swizzled 16B slot
            bf16x8 aF[2], bF[4];
#pragma unroll
            for (int i = 0; i < 2; ++i)
                aF[i] = *(const bf16x8*)&cl[(wmo + i * 16 + fr) * BK + sl];
#pragma unroll
            for (int j = 0; j < 4; ++j)
                bF[j] = *(const bf16x8*)&cl[ASZ + (wno + j * 16 + fr) * BK + sl];
#pragma unroll
            for (int i = 0; i < 2; ++i)
#pragma unroll
                for (int j = 0; j < 4; ++j)
                    acc[i][j] = __builtin_amdgcn_mfma_f32_16x16x32_bf16(aF[i], bF[j], acc[i][j], 0, 0, 0);
        }
    }
#undef STAGE

    // ---- epilogue: C layout col = lane&15, row = (lane>>4)*4 + reg ----
    const int rowg = (lane >> 4) * 4;
#pragma unroll
    for (int j = 0; j < 4; ++j) {
        const int n = n0 + bn + wno + j * 16 + fr;
        float bs = 0.0f, cpf[8], rwf = 0.0f, s1 = 0.0f;
        if constexpr (EPI < 3) bs = bias[n];
        if constexpr (EPI < 2) {
#pragma unroll
            for (int q = 0; q < 8; ++q) cpf[q] = cp[(size_t)n * 9 + q];
            rwf = rw[n];
        }
        if constexpr (EPI == 0) s1 = S1[n];
        const int s = n & 7;  // generator slot: {0,1}->sx, {2,3}->sy, {4..7}->identity
#pragma unroll
        for (int i = 0; i < 2; ++i) {
            const int m0 = bm + wmo + i * 16 + rowg;
#pragma unroll
            for (int r = 0; r < 4; ++r) {
                const int m = m0 + r;
                float v = acc[i][j][r];
                if constexpr (EPI == 0) v = (v - mu[m] * s1) * rstd[m] + bs;
                else if constexpr (EPI < 3) v += bs;
                if constexpr (EPI < 2) {
                    v = kan_spline(tanhf(v), cpf, rwf);
                    float p = __shfl_xor(v, 1, 64);  // partner col n^1 lives in lane^1
                    p = fminf(fmaxf(p, -1.0f), 1.0f);
                    if (s < 4) v += ((s == 2) ? -0.05f : 0.05f) * p;
                }
                if constexpr (EPI == 2)      ((float*)outp)[(size_t)m * Nld + n] = v;
                else if constexpr (EPI == 3) ((float*)outp)[(size_t)kh * khoff + (size_t)m * Nld + n] = v;
                else ((unsigned short*)outp)[(size_t)m * Nld + n] = f2b(v);
            }
        }
    }
}

// ============================================================================
// Legacy 64x64 kernel kept ONLY for the small-workspace insurance path
// (in-loop f32->bf16 conversion variants BSRC 1/2). Unchanged.
// ============================================================================
template <int EPI, int BSRC>
__global__ __launch_bounds__(256, 2)
void gemm_kan(const void* __restrict__ Av, const void* __restrict__ Bv,
              const float* __restrict__ bias, const float* __restrict__ cp,
              const float* __restrict__ rw, const float* __restrict__ mu,
              const float* __restrict__ rstd, const float* __restrict__ S1,
              void* __restrict__ outp,
              int Nld, int n0, int Ktot, int lda, int ldb)
{
    constexpr int BM = 64, BN = 64, BK = 64, LDP = 72;
    constexpr bool SPL = (BSRC == 2);
    constexpr int OFF_B  = BM * LDP;
    constexpr int OFF_LO = (BM + BN) * LDP;
    __shared__ unsigned short lds[(SPL ? 2 : 1) * (BM + BN) * LDP];

    const int tid  = threadIdx.x;
    const int lane = tid & 63;
    const int wid  = tid >> 6;
    const int bm = blockIdx.x * BM;
    const int bn = blockIdx.y * BN;
    const int wmo = (wid >> 1) * 32;
    const int wno = (wid & 1) * 32;
    const int fr = lane & 15;
    const int kq = lane >> 4;
    const int sar = tid >> 3, sac = (tid & 7) << 3;
    const int sfr = tid >> 2, sfc = (tid & 3) << 4;

    f32x4 acc[2][2] = {};

    uint4 pA0 = {}, pA1 = {}, pB0 = {}, pB1 = {};
    const unsigned short* Ab = (const unsigned short*)Av;
    const unsigned short* Bb = (const unsigned short*)Bv;
    const size_t a0 = (size_t)(bm + sar) * lda + sac;
    const size_t a1 = (size_t)(bm + 32 + sar) * lda + sac;
    const size_t b0 = (size_t)(bn + sar) * ldb + sac;
    const size_t b1 = (size_t)(bn + 32 + sar) * ldb + sac;
    if constexpr (BSRC == 0) {
        pA0 = *(const uint4*)(Ab + a0);
        pA1 = *(const uint4*)(Ab + a1);
        pB0 = *(const uint4*)(Bb + b0);
        pB1 = *(const uint4*)(Bb + b1);
    }

    for (int k0 = 0; k0 < Ktot; k0 += BK) {
        if constexpr (BSRC == 0) {
            *(uint4*)&lds[sar * LDP + sac] = pA0;
            *(uint4*)&lds[(32 + sar) * LDP + sac] = pA1;
            *(uint4*)&lds[OFF_B + sar * LDP + sac] = pB0;
            *(uint4*)&lds[OFF_B + (32 + sar) * LDP + sac] = pB1;
        } else {
            {
                const float* g = (const float*)Bv + (size_t)(bn + sfr) * ldb + k0 + sfc;
                float4 u0 = ((const float4*)g)[0];
                float4 u1 = ((const float4*)g)[1];
                float4 u2 = ((const float4*)g)[2];
                float4 u3 = ((const float4*)g)[3];
                float v[16] = {u0.x,u0.y,u0.z,u0.w, u1.x,u1.y,u1.z,u1.w,
                               u2.x,u2.y,u2.z,u2.w, u3.x,u3.y,u3.z,u3.w};
                unsigned short hi[16], lo[16];
#pragma unroll
                for (int i = 0; i < 16; ++i) {
                    hi[i] = f2b(v[i]);
                    if (SPL) lo[i] = f2b(v[i] - b2f(hi[i]));
                }
                unsigned short* d = &lds[OFF_B + sfr * LDP + sfc];
                ((uint4*)d)[0] = *(const uint4*)&hi[0];
                ((uint4*)d)[1] = *(const uint4*)&hi[8];
                if constexpr (SPL) {
                    unsigned short* dl = d + OFF_LO;
                    ((uint4*)dl)[0] = *(const uint4*)&lo[0];
                    ((uint4*)dl)[1] = *(const uint4*)&lo[8];
                }
            }
            if constexpr (SPL) {
                const float* g = (const float*)Av + (size_t)(bm + sfr) * lda + k0 + sfc;
                float4 u0 = ((const float4*)g)[0];
                float4 u1 = ((const float4*)g)[1];
                float4 u2 = ((const float4*)g)[2];
                float4 u3 = ((const float4*)g)[3];
                float v[16] = {u0.x,u0.y,u0.z,u0.w, u1.x,u1.y,u1.z,u1.w,
                               u2.x,u2.y,u2.z,u2.w, u3.x,u3.y,u3.z,u3.w};
                unsigned short hi[16], lo[16];
#pragma unroll
                for (int i = 0; i < 16; ++i) {
                    hi[i] = f2b(v[i]);
                    lo[i] = f2b(v[i] - b2f(hi[i]));
                }
                unsigned short* d = &lds[sfr * LDP + sfc];
                ((uint4*)d)[0] = *(const uint4*)&hi[0];
                ((uint4*)d)[1] = *(const uint4*)&hi[8];
                unsigned short* dl = d + OFF_LO;
                ((uint4*)dl)[0] = *(const uint4*)&lo[0];
                ((uint4*)dl)[1] = *(const uint4*)&lo[8];
            } else {
                *(uint4*)&lds[sar * LDP + sac] = *(const uint4*)(Ab + a0 + k0);
                *(uint4*)&lds[(32 + sar) * LDP + sac] = *(const uint4*)(Ab + a1 + k0);
            }
        }
        __syncthreads();
        if constexpr (BSRC == 0) {
            if (k0 + BK < Ktot) {
                const int kn = k0 + BK;
                const int ak = (EPI == 0) ? (kn < 4096 ? kn : kn - 4096) : kn;
                const int bk = (EPI == 0) ? (kn < 2048 ? kn : kn - 2048) : kn;
                pA0 = *(const uint4*)(Ab + a0 + ak);
                pA1 = *(const uint4*)(Ab + a1 + ak);
                pB0 = *(const uint4*)(Bb + b0 + bk);
                pB1 = *(const uint4*)(Bb + b1 + bk);
            }
        }
#pragma unroll
        for (int s = 0; s < 2; ++s) {
            const int cc = (s * 4 + kq) << 3;
            bf16x8 aF[2], bF[2];
#pragma unroll
            for (int i = 0; i < 2; ++i)
                aF[i] = *(const bf16x8*)&lds[(wmo + i * 16 + fr) * LDP + cc];
#pragma unroll
            for (int j = 0; j < 2; ++j)
                bF[j] = *(const bf16x8*)&lds[OFF_B + (wno + j * 16 + fr) * LDP + cc];
#pragma unroll
            for (int i = 0; i < 2; ++i)
#pragma unroll
                for (int j = 0; j < 2; ++j)
                    acc[i][j] = __builtin_amdgcn_mfma_f32_16x16x32_bf16(aF[i], bF[j], acc[i][j], 0, 0, 0);
            if constexpr (SPL) {
                bf16x8 aL[2], bL[2];
#pragma unroll
                for (int i = 0; i < 2; ++i)
                    aL[i] = *(const bf16x8*)&lds[OFF_LO + (wmo + i * 16 + fr) * LDP + cc];
#pragma unroll
                for (int i = 0; i < 2; ++i)
#pragma unroll
                    for (int j = 0; j < 2; ++j)
                        acc[i][j] = __builtin_amdgcn_mfma_f32_16x16x32_bf16(aL[i], bF[j], acc[i][j], 0, 0, 0);
#pragma unroll
                for (int j = 0; j < 2; ++j)
                    bL[j] = *(const bf16x8*)&lds[OFF_LO + OFF_B + (wno + j * 16 + fr) * LDP + cc];
#pragma unroll
                for (int i = 0; i < 2; ++i)
#pragma unroll
                    for (int j = 0; j < 2; ++j)
                        acc[i][j] = __builtin_amdgcn_mfma_f32_16x16x32_bf16(aF[i], bL[j], acc[i][j], 0, 0, 0);
            }
        }
        __syncthreads();
    }

    const int rowg = (lane >> 4) * 4;
#pragma unroll
    for (int j = 0; j < 2; ++j) {
        const int n = n0 + bn + wno + j * 16 + fr;
        const float bs = bias[n];
        float cpf[8], rwf = 0.0f, s1 = 0.0f;
        if (EPI < 2) {
#pragma unroll
            for (int q = 0; q < 8; ++q) cpf[q] = cp[(size_t)n * 9 + q];
            rwf = rw[n];
        }
        if (EPI == 0) s1 = S1[n];
        const int s = n & 7;
#pragma unroll
        for (int i = 0; i < 2; ++i) {
            const int m0 = bm + wmo + i * 16 + rowg;
#pragma unroll
            for (int r = 0; r < 4; ++r) {
                const int m = m0 + r;
                float v = acc[i][j][r];
                if (EPI == 0) v = (v - mu[m] * s1) * rstd[m] + bs;
                else          v += bs;
                if (EPI < 2) {
                    v = kan_spline(tanhf(v), cpf, rwf);
                    float p = __shfl_xor(v, 1, 64);
                    p = fminf(fmaxf(p, -1.0f), 1.0f);
                    if (s < 4) v += ((s == 2) ? -0.05f : 0.05f) * p;
                }
                if (EPI == 2) ((float*)outp)[(size_t)m * Nld + n] = v;
                else ((unsigned short*)outp)[(size_t)m * Nld + n] = f2b(v);
            }
        }
    }
}

extern "C" void kernel_launch(void* const* d_in, const int* in_sizes, int n_in,
                              void* d_out, int out_size, void* d_ws, size_t ws_size,
                              hipStream_t stream) {
    const float* x    = (const float*)d_in[0];
    const float* W1   = (const float*)d_in[1];
    const float* b1   = (const float*)d_in[2];
    const float* cp1  = (const float*)d_in[3];
    const float* rw1  = (const float*)d_in[4];
    const float* W2   = (const float*)d_in[5];
    const float* b2   = (const float*)d_in[6];
    const float* cp2  = (const float*)d_in[7];
    const float* rw2  = (const float*)d_in[8];
    const float* W3   = (const float*)d_in[9];
    const float* b3   = (const float*)d_in[10];
    const float* cp3  = (const float*)d_in[11];
    const float* rw3  = (const float*)d_in[12];
    const float* Wout = (const float*)d_in[13];
    const float* bout = (const float*)d_in[14];

    char* ws = (char*)d_ws;
    float* mu   = (float*)(ws);                  // 1024 f32
    float* rstd = (float*)(ws + 4096);           // 1024 f32
    float* S1   = (float*)(ws + 8192);           // 4096 f32
    unsigned short* A2 = (unsigned short*)(ws + 32768);              // 1024x4096 bf16 (8MB)
    unsigned short* A3 = (unsigned short*)(ws + 32768 + 8388608);    // 1024x4096 bf16 (8MB)
    unsigned short* Asplit = A3;                  // x split lives in A3 slot until L2 writes it
    unsigned short* Wb = (unsigned short*)(ws + 32768 + 2 * 8388608); // 32MB region
    // split-K partials: half 0 in the (dead) A2 region, half 1 in the free
    // 8MB tail of Wb (after W3b 16MB + Woutb 8MB). khoff links them.
    float* Pk0 = (float*)(ws + 32768);                               // 8MB
    const int KHOFF = 10582016;  // float offset: Pk1 = ws + 42360832 (Wb tail)
    unsigned short* A4v = A3;    // L3 output -> A3 region (dead after L3 gemm)
    const size_t NEED_FULL = 32768 + 2 * 8388608 + 33554432;  // 50.4 MB
    const size_t NEED_HALF = 32768 + 2 * 8388608 + 16777216;  // 33.6 MB

    if (ws_size >= NEED_FULL) {
        // 9 launches: pre_all + 4 gemms (all 512-block = 2 blocks/CU) +
        // 2 cvt + 2 split-K reduces.
        pre_all<<<5120, 256, 0, stream>>>(x, W1, mu, rstd, S1, Asplit, Wb);
        gemm_kan2<0><<<dim3(16, 32), 256, 0, stream>>>(
            Asplit, Wb, b1, cp1, rw1, mu, rstd, S1, A2, 4096, 0, 6144, 4096, 4096, 32, 0);
        cvt_kernel<<<8192, 256, 0, stream>>>(W2, Wb);
        gemm_kan2<1><<<dim3(16, 32), 256, 0, stream>>>(
            A2, Wb, b2, cp2, rw2, nullptr, nullptr, nullptr, A3, 4096, 0, 4096, 4096, 4096, 32, 0);
        cvt2_kernel<<<6144, 256, 0, stream>>>(W3, Wb, 4096, Wout, Wb + 8388608);
        // L3: split-K=2 -> 512 blocks (2/CU). A2 dead (read by L2 done).
        gemm_kan2<3><<<dim3(16, 32), 256, 0, stream>>>(
            A3, Wb, nullptr, nullptr, nullptr, nullptr, nullptr, nullptr,
            Pk0, 2048, 0, 2048, 4096, 4096, 16, KHOFF);
        reduce_epi<1><<<1024, 256, 0, stream>>>(
            Pk0, Pk0 + KHOFF, b3, cp3, rw3, A4v, 2048);
        // L4: split-K=2. A4 (in A3 region) as input; partials reuse Pk0/Pk1.
        gemm_kan2<3><<<dim3(16, 32), 256, 0, stream>>>(
            A4v, Wb + 8388608, nullptr, nullptr, nullptr, nullptr, nullptr, nullptr,
            Pk0, 2048, 0, 1024, 2048, 2048, 16, KHOFF);
        reduce_epi<2><<<1024, 256, 0, stream>>>(
            Pk0, Pk0 + KHOFF, bout, nullptr, nullptr, d_out, 2048);
    } else if (ws_size >= NEED_HALF) {
        unsigned short* A4 = A2;
        ln_stats_kernel<<<1024, 256, 0, stream>>>(x, mu, rstd);
        rowsum_kernel<<<1024, 256, 0, stream>>>(W1, S1, 2048);
        split2_kernel<<<1024, 256, 0, stream>>>(x, Asplit, 2048);
        for (int h = 0; h < 2; ++h) {
            split2_kernel<<<2048, 256, 0, stream>>>(W1 + (size_t)h * 2048 * 2048, Wb, 2048);
            gemm_kan2<0><<<dim3(16, 16), 256, 0, stream>>>(
                Asplit, Wb, b1, cp1, rw1, mu, rstd, S1, A2, 4096, h * 2048, 6144, 4096, 4096, 16, 0);
        }
        for (int h = 0; h < 2; ++h) {
            cvt_kernel<<<4096, 256, 0, stream>>>(W2 + (size_t)h * 2048 * 4096, Wb);
            gemm_kan2<1><<<dim3(16, 16), 256, 0, stream>>>(
                A2, Wb, b2, cp2, rw2, nullptr, nullptr, nullptr, A3, 4096, h * 2048, 4096, 4096, 4096, 16, 0);
        }
        cvt_kernel<<<4096, 256, 0, stream>>>(W3, Wb);
        gemm_kan2<1><<<dim3(16, 16), 256, 0, stream>>>(
            A3, Wb, b3, cp3, rw3, nullptr, nullptr, nullptr, A4, 2048, 0, 4096, 4096, 4096, 16, 0);
        cvt_kernel<<<2048, 256, 0, stream>>>(Wout, Wb);
        gemm_kan2<2><<<dim3(16, 16), 256, 0, stream>>>(
            A4, Wb, bout, nullptr, nullptr, nullptr, nullptr, nullptr, d_out, 2048, 0, 2048, 2048, 2048, 16, 0);
    } else {
        // 16.8 MB insurance path: in-loop conversion (round-4-proven staging)
        unsigned short* A4 = A2;
        ln_stats_kernel<<<1024, 256, 0, stream>>>(x, mu, rstd);
        rowsum_kernel<<<1024, 256, 0, stream>>>(W1, S1, 2048);
        gemm_kan<0, 2><<<dim3(16, 64), 256, 0, stream>>>(
            x, W1, b1, cp1, rw1, mu, rstd, S1, A2, 4096, 0, 2048, 2048, 2048);
        gemm_kan<1, 1><<<dim3(16, 64), 256, 0, stream>>>(
            A2, W2, b2, cp2, rw2, nullptr, nullptr, nullptr, A3, 4096, 0, 4096, 4096, 4096);
        gemm_kan<1, 1><<<dim3(16, 32), 256, 0, stream>>>(
            A3, W3, b3, cp3, rw3, nullptr, nullptr, nullptr, A4, 2048, 0, 4096, 4096, 4096);
        gemm_kan<2, 1><<<dim3(16, 32), 256, 0, stream>>>(
            A4, Wout, bout, nullptr, nullptr, nullptr, nullptr, nullptr, d_out, 2048, 0, 2048, 2048, 2048);
    }
}

// Round 9
// 381.146 us; speedup vs baseline: 1.0314x; 1.0314x over previous
//
#include <hip/hip_runtime.h>

typedef __attribute__((ext_vector_type(8))) short bf16x8;
typedef __attribute__((ext_vector_type(4))) float f32x4;

__device__ __forceinline__ float b2f(unsigned short u) {
    union { unsigned int i; float f; } x; x.i = ((unsigned int)u) << 16; return x.f;
}
__device__ __forceinline__ unsigned short f2b(float f) {
    union { float f; unsigned int i; } x; x.f = f;
    unsigned int r = x.i + 0x7fffu + ((x.i >> 16) & 1u);  // RNE
    return (unsigned short)(r >> 16);
}

// async global->LDS, 16 B per lane (wave-uniform LDS base + lane*16 layout)
__device__ __forceinline__ void gl16(unsigned short* l, const unsigned short* g) {
    __builtin_amdgcn_global_load_lds((__attribute__((address_space(1))) void*)g,
                                     (__attribute__((address_space(3))) void*)l, 16, 0, 0);
}

// Partial Cox-de Boor exactly as the reference leaves it:
// cols 0-4 degree 3, col 5 degree 2, col 6 degree 1, col 7 degree 0.
// knots = [-1,-1,-1,-1,-0.6,-0.2,0.2,0.6,1,1,1,1]
__device__ __forceinline__ float kan_spline(float t, const float* cpf, float rwf) {
    float c3 = (t >= -1.0f && t < -0.6f) ? 1.0f : 0.0f;
    float c4 = (t >= -0.6f && t < -0.2f) ? 1.0f : 0.0f;
    float c5 = (t >= -0.2f && t <  0.2f) ? 1.0f : 0.0f;
    float c6 = (t >=  0.2f && t <  0.6f) ? 1.0f : 0.0f;
    float c7 = (t >=  0.6f && t <  1.0f) ? 1.0f : 0.0f;
    float d2 = (-0.6f - t) * 2.5f * c3;
    float d3 = (t + 1.0f) * 2.5f * c3 + (-0.2f - t) * 2.5f * c4;
    float d4 = (t + 0.6f) * 2.5f * c4 + ( 0.2f - t) * 2.5f * c5;
    float d5 = (t + 0.2f) * 2.5f * c5 + ( 0.6f - t) * 2.5f * c6;
    float d6 = (t - 0.2f) * 2.5f * c6 + ( 1.0f - t) * 2.5f * c7;
    float e1 = (-0.6f - t) * 2.5f  * d2;
    float e2 = (t + 1.0f) * 2.5f  * d2 + (-0.2f - t) * 1.25f * d3;
    float e3 = (t + 1.0f) * 1.25f * d3 + ( 0.2f - t) * 1.25f * d4;
    float e4 = (t + 0.6f) * 1.25f * d4 + ( 0.6f - t) * 1.25f * d5;
    float e5 = (t + 0.2f) * 1.25f * d5 + ( 1.0f - t) * 1.25f * d6;
    const float r12 = 1.0f / 1.2f;
    float f0 = (-0.6f - t) * 2.5f  * e1;
    float f1 = (t + 1.0f) * 2.5f  * e1 + (-0.2f - t) * 1.25f * e2;
    float f2 = (t + 1.0f) * 1.25f * e2 + ( 0.2f - t) * r12   * e3;
    float f3 = (t + 1.0f) * r12   * e3 + ( 0.6f - t) * r12   * e4;
    float f4 = (t + 0.6f) * r12   * e4 + ( 1.0f - t) * r12   * e5;
    float sp = f0*cpf[0] + f1*cpf[1] + f2*cpf[2] + f3*cpf[3] + f4*cpf[4]
             + e5*cpf[5] + d6*cpf[6] + c7*cpf[7];
    float v = sp * rwf;
    return fminf(fmaxf(v, -10.0f), 10.0f);
}

// per-row mean / rstd of x[1024,2048] f32, fp64 accumulate (fallback paths)
__global__ void ln_stats_kernel(const float* __restrict__ x,
                                float* __restrict__ mu, float* __restrict__ rstd) {
    const int row = blockIdx.x;
    const float* p = x + (size_t)row * 2048 + threadIdx.x * 8;
    double s = 0.0, q = 0.0;
#pragma unroll
    for (int i = 0; i < 8; ++i) { float v = p[i]; s += v; q += (double)v * v; }
    for (int o = 32; o > 0; o >>= 1) { s += __shfl_down(s, o, 64); q += __shfl_down(q, o, 64); }
    __shared__ double shs[4], shq[4];
    const int lane = threadIdx.x & 63, w = threadIdx.x >> 6;
    if (lane == 0) { shs[w] = s; shq[w] = q; }
    __syncthreads();
    if (threadIdx.x == 0) {
        double S = shs[0] + shs[1] + shs[2] + shs[3];
        double Q = shq[0] + shq[1] + shq[2] + shq[3];
        double m = S / 2048.0;
        double var = Q / 2048.0 - m * m;
        mu[row] = (float)m;
        rstd[row] = (float)(1.0 / sqrt(var + 1e-5));
    }
}

// S[n] = sum_k W[n,k] (f32 W); one wave per row, 4 rows per block (fallback)
__global__ void rowsum_kernel(const float* __restrict__ W,
                              float* __restrict__ S, int K) {
    const int lane = threadIdx.x & 63, w = threadIdx.x >> 6;
    const int row = blockIdx.x * 4 + w;
    const float* p = W + (size_t)row * K;
    double s = 0.0;
    for (int c = lane * 8; c < K; c += 512) {
#pragma unroll
        for (int i = 0; i < 8; ++i) s += p[c + i];
    }
    for (int o = 32; o > 0; o >>= 1) s += __shfl_down(s, o, 64);
    if (lane == 0) S[row] = (float)s;
}

// [R,C] f32 -> [R,2C] bf16 as [hi | lo]; one block per row, C = 2048 (fallback)
__global__ void split2_kernel(const float* __restrict__ src,
                              unsigned short* __restrict__ dst, int C) {
    const int r = blockIdx.x;
    const int c = threadIdx.x * 8;
    const float* p = src + (size_t)r * C + c;
    float4 u0 = ((const float4*)p)[0];
    float4 u1 = ((const float4*)p)[1];
    float v[8] = {u0.x, u0.y, u0.z, u0.w, u1.x, u1.y, u1.z, u1.w};
    unsigned short hi[8], lo[8];
#pragma unroll
    for (int i = 0; i < 8; ++i) {
        hi[i] = f2b(v[i]);
        lo[i] = f2b(v[i] - b2f(hi[i]));
    }
    unsigned short* d = dst + (size_t)r * 2 * C + c;
    *(uint4*)d = *(const uint4*)hi;
    *(uint4*)(d + C) = *(const uint4*)lo;
}

// ============================================================================
// pre_all: fused preprocessing, ONE launch (round-7 proven).
// blocks [0,1024):    x row r -> LN stats + hi|lo split into Asplit.
// blocks [1024,5120): W1 row r -> row sum (fp64) into S1 + hi|lo split -> W1b.
// ============================================================================
__global__ void pre_all(const float* __restrict__ x, const float* __restrict__ W1,
                        float* __restrict__ mu, float* __restrict__ rstd,
                        float* __restrict__ S1,
                        unsigned short* __restrict__ Asplit,
                        unsigned short* __restrict__ W1b) {
    const int tid = threadIdx.x;
    const int lane = tid & 63, w = tid >> 6;
    const int c = tid * 8;
    __shared__ double shs[4], shq[4];
    if (blockIdx.x < 1024) {
        const int r = blockIdx.x;
        const float* p = x + (size_t)r * 2048 + c;
        float4 u0 = ((const float4*)p)[0];
        float4 u1 = ((const float4*)p)[1];
        float v[8] = {u0.x, u0.y, u0.z, u0.w, u1.x, u1.y, u1.z, u1.w};
        double s = 0.0, q = 0.0;
#pragma unroll
        for (int i = 0; i < 8; ++i) { s += v[i]; q += (double)v[i] * v[i]; }
        for (int o = 32; o > 0; o >>= 1) { s += __shfl_down(s, o, 64); q += __shfl_down(q, o, 64); }
        if (lane == 0) { shs[w] = s; shq[w] = q; }
        __syncthreads();
        if (tid == 0) {
            double S = shs[0] + shs[1] + shs[2] + shs[3];
            double Q = shq[0] + shq[1] + shq[2] + shq[3];
            double m = S / 2048.0;
            double var = Q / 2048.0 - m * m;
            mu[r] = (float)m;
            rstd[r] = (float)(1.0 / sqrt(var + 1e-5));
        }
        unsigned short hi[8], lo[8];
#pragma unroll
        for (int i = 0; i < 8; ++i) {
            hi[i] = f2b(v[i]);
            lo[i] = f2b(v[i] - b2f(hi[i]));
        }
        unsigned short* d = Asplit + (size_t)r * 4096 + c;
        *(uint4*)d = *(const uint4*)hi;
        *(uint4*)(d + 2048) = *(const uint4*)lo;
    } else {
        const int r = blockIdx.x - 1024;
        const float* p = W1 + (size_t)r * 2048 + c;
        float4 u0 = ((const float4*)p)[0];
        float4 u1 = ((const float4*)p)[1];
        float v[8] = {u0.x, u0.y, u0.z, u0.w, u1.x, u1.y, u1.z, u1.w};
        double s = 0.0;
#pragma unroll
        for (int i = 0; i < 8; ++i) s += v[i];
        for (int o = 32; o > 0; o >>= 1) s += __shfl_down(s, o, 64);
        if (lane == 0) shs[w] = s;
        __syncthreads();
        if (tid == 0) S1[r] = (float)(shs[0] + shs[1] + shs[2] + shs[3]);
        unsigned short hi[8], lo[8];
#pragma unroll
        for (int i = 0; i < 8; ++i) {
            hi[i] = f2b(v[i]);
            lo[i] = f2b(v[i] - b2f(hi[i]));
        }
        unsigned short* d = W1b + (size_t)r * 4096 + c;
        *(uint4*)d = *(const uint4*)hi;
        *(uint4*)(d + 2048) = *(const uint4*)lo;
    }
}

// flat f32 -> bf16, 8 el/thread
__global__ void cvt_kernel(const float* __restrict__ src,
                           unsigned short* __restrict__ dst) {
    const size_t i = ((size_t)blockIdx.x * 256 + threadIdx.x) * 8;
    float4 u0 = ((const float4*)(src + i))[0];
    float4 u1 = ((const float4*)(src + i))[1];
    float v[8] = {u0.x, u0.y, u0.z, u0.w, u1.x, u1.y, u1.z, u1.w};
    unsigned short t[8];
#pragma unroll
    for (int q = 0; q < 8; ++q) t[q] = f2b(v[q]);
    *(uint4*)(dst + i) = *(const uint4*)t;
}

// two-range flat f32 -> bf16 in one launch (W3 + Wout): kills one launch.
__global__ void cvt2_kernel(const float* __restrict__ s1, unsigned short* __restrict__ d1,
                            int nb1, const float* __restrict__ s2,
                            unsigned short* __restrict__ d2) {
    const int b = blockIdx.x;
    const float* src = (b < nb1) ? s1 : s2;
    unsigned short* dst = (b < nb1) ? d1 : d2;
    const int bb = (b < nb1) ? b : b - nb1;
    const size_t i = ((size_t)bb * 256 + threadIdx.x) * 8;
    float4 u0 = ((const float4*)(src + i))[0];
    float4 u1 = ((const float4*)(src + i))[1];
    float v[8] = {u0.x, u0.y, u0.z, u0.w, u1.x, u1.y, u1.z, u1.w};
    unsigned short t[8];
#pragma unroll
    for (int q = 0; q < 8; ++q) t[q] = f2b(v[q]);
    *(uint4*)(dst + i) = *(const uint4*)t;
}

// ============================================================================
// gemm_kan1: L1 FUSED hi/lo kernel. C = (xhi+xlo) @ (Whi+Wlo)^T approx via
// 3 MFMA groups per K-slice: hi*hi + lo*hi + hi*lo (same math as the old
// 3-segment Ktot=6144 mapping, but each slice's operands staged ONCE).
// Per logical K=32 slice: 24 KB staged (was 36), 48 KB ds_read (was 72),
// 1 barrier (was 3), same MFMA count -> serial LDS-port+L2 bound -33%.
// BM=64 BN=128 BK=32, 4 waves 2x2 (wave tile 32x64, acc[2][4]).
// LDS buffer = [Ahi 4K][Alo 4K][Bhi 8K][Blo 8K] = 24 KB; triple = 72 KB
// (same footprint as round-7 kernel -> 2 blocks/CU preserved).
// Schedule: round-3-proven counted-vmcnt triple-buffer 2-deep, vmcnt(6).
// Swizzle: [rows][32] tiles, 16B slot XOR'd with (row&3): source-side on
// the global col + read-side on kq (rule #21, LDS dest linear). Uniform
// 8 dwords/bank per wave b128 read -> conflict-free.
// Epilogue: lin = rstd*(acc - mu*S1) + bias, KAN+NCT, bf16 out.
// ============================================================================
__global__ __launch_bounds__(256, 2)
void gemm_kan1(const unsigned short* __restrict__ Ab,
               const unsigned short* __restrict__ Bb,
               const float* __restrict__ bias, const float* __restrict__ cp,
               const float* __restrict__ rw, const float* __restrict__ mu,
               const float* __restrict__ rstd, const float* __restrict__ S1,
               unsigned short* __restrict__ outp,
               int Nld, int Klog, int lda, int ldb)
{
    constexpr int BM = 64, BN = 128, BK = 32;
    constexpr int AHI = 0, ALO = 2048, BHI = 4096, BLO = 8192;  // short offs
    constexpr int BUF = 12288;          // 24 KB in shorts
    __shared__ unsigned short lds[3 * BUF];  // 72 KB triple buffer

    const int tid  = threadIdx.x;
    const int lane = tid & 63;
    const int wid  = tid >> 6;

    // XCD-chunked bijective swizzle (nwg = 512, %8==0)
    const int gx = gridDim.x;
    int flat = blockIdx.y * gx + blockIdx.x;
    const int nwg = gx * gridDim.y;
    if ((nwg & 7) == 0) flat = (flat & 7) * (nwg >> 3) + (flat >> 3);
    const int bm = (flat % gx) * BM;
    const int bn = (flat / gx) * BN;

    const int wmo = (wid >> 1) * 32;   // wave row offset within BM
    const int wno = (wid & 1) * 64;    // wave col offset within BN
    const int fr = lane & 15;
    const int kq = lane >> 4;
    const int slotr = (kq ^ (fr & 3)) << 3;  // read-side swizzled slot (shorts)

    // staging: unit = (row, slot) with slot = tid&3, row = tid>>2.
    // A regions: 256 units (1/thread). B regions: 512 units (2/thread).
    const int rA = tid >> 2, sA = tid & 3;
    const int rB1 = rA + 64;           // (tid+256)>>2 ; (tid+256)&3 == sA
    // global source col pre-swizzled: ((slot ^ (row&3)) << 3)
    const size_t aoff  = (size_t)(bm + rA)  * lda + ((sA ^ (rA  & 3)) << 3);
    const size_t boff0 = (size_t)(bn + rA)  * ldb + ((sA ^ (rA  & 3)) << 3);
    const size_t boff1 = (size_t)(bn + rB1) * ldb + ((sA ^ (rB1 & 3)) << 3);

    f32x4 acc[2][4] = {};

#define STAGE(BSEL, K) do {                                           \
    unsigned short* l_ = &lds[(BSEL) * BUF];                          \
    gl16(l_ + AHI + tid * 8,         Ab + aoff  + (K));               \
    gl16(l_ + ALO + tid * 8,         Ab + aoff  + 2048 + (K));        \
    gl16(l_ + BHI + tid * 8,         Bb + boff0 + (K));               \
    gl16(l_ + BHI + (tid + 256) * 8, Bb + boff1 + (K));               \
    gl16(l_ + BLO + tid * 8,         Bb + boff0 + 2048 + (K));        \
    gl16(l_ + BLO + (tid + 256) * 8, Bb + boff1 + 2048 + (K));        \
} while (0)

    const int nt = Klog / BK;          // 64
    STAGE(0, 0);
    STAGE(1, BK);

    for (int t = 0; t < nt; ++t) {
        // counted drain: most recent STAGE (6 loads) stays in flight across
        // the barrier; own t-tile loads (issued 2 iters ago) are complete.
        if (t + 1 < nt) asm volatile("s_waitcnt vmcnt(6)" ::: "memory");
        else            asm volatile("s_waitcnt vmcnt(0)" ::: "memory");
        __builtin_amdgcn_s_barrier();
        __builtin_amdgcn_sched_barrier(0);  // pin ds_reads below the barrier
        if (t + 2 < nt) STAGE((t + 2) % 3, (t + 2) * BK);
        const unsigned short* cl = &lds[(t % 3) * BUF];
        bf16x8 aH[2], aL[2], bH[4], bL[4];
#pragma unroll
        for (int i = 0; i < 2; ++i) {
            const int ro = (wmo + i * 16 + fr) * 32 + slotr;
            aH[i] = *(const bf16x8*)&cl[AHI + ro];
            aL[i] = *(const bf16x8*)&cl[ALO + ro];
        }
#pragma unroll
        for (int j = 0; j < 4; ++j) {
            const int ro = (wno + j * 16 + fr) * 32 + slotr;
            bH[j] = *(const bf16x8*)&cl[BHI + ro];
            bL[j] = *(const bf16x8*)&cl[BLO + ro];
        }
#pragma unroll
        for (int i = 0; i < 2; ++i)
#pragma unroll
            for (int j = 0; j < 4; ++j)
                acc[i][j] = __builtin_amdgcn_mfma_f32_16x16x32_bf16(aH[i], bH[j], acc[i][j], 0, 0, 0);
#pragma unroll
        for (int i = 0; i < 2; ++i)
#pragma unroll
            for (int j = 0; j < 4; ++j)
                acc[i][j] = __builtin_amdgcn_mfma_f32_16x16x32_bf16(aL[i], bH[j], acc[i][j], 0, 0, 0);
#pragma unroll
        for (int i = 0; i < 2; ++i)
#pragma unroll
            for (int j = 0; j < 4; ++j)
                acc[i][j] = __builtin_amdgcn_mfma_f32_16x16x32_bf16(aH[i], bL[j], acc[i][j], 0, 0, 0);
    }
#undef STAGE

    // ---- epilogue: C layout col = lane&15, row = (lane>>4)*4 + reg ----
    const int rowg = (lane >> 4) * 4;
#pragma unroll
    for (int j = 0; j < 4; ++j) {
        const int n = bn + wno + j * 16 + fr;
        const float bs = bias[n];
        float cpf[8];
#pragma unroll
        for (int q = 0; q < 8; ++q) cpf[q] = cp[(size_t)n * 9 + q];
        const float rwf = rw[n];
        const float s1 = S1[n];
        const int s = n & 7;  // generator slot: {0,1}->sx, {2,3}->sy, {4..7}->identity
#pragma unroll
        for (int i = 0; i < 2; ++i) {
            const int m0 = bm + wmo + i * 16 + rowg;
#pragma unroll
            for (int r = 0; r < 4; ++r) {
                const int m = m0 + r;
                float v = acc[i][j][r];
                v = (v - mu[m] * s1) * rstd[m] + bs;
                v = kan_spline(tanhf(v), cpf, rwf);
                float p = __shfl_xor(v, 1, 64);  // partner col n^1 lives in lane^1
                p = fminf(fmaxf(p, -1.0f), 1.0f);
                if (s < 4) v += ((s == 2) ? -0.05f : 0.05f) * p;
                outp[(size_t)m * Nld + n] = f2b(v);
            }
        }
    }
}

// ============================================================================
// gemm_kan2: ROUND-3 EXACT core (measured 79.5 us, reproduced 4x).
// C[1024 x Ncols] = A @ B^T, bf16 inputs, fused LN-fold/KAN/NCT.
// BM=64 BN=128 BK=64, 4 waves 2x2 (wave tile 32x64, acc[2][4]); 512-block
// grids = 2 blocks/CU where possible. Triple-buffered LDS (72 KB), 2-deep
// global_load_lds prefetch, ONE raw s_barrier per K-step preceded by COUNTED
// s_waitcnt vmcnt(6). sched_barrier pins ds_reads below the barrier. XOR
// bank-conflict swizzle source+read side, LDS dest linear (0 conflicts).
// XCD-chunked grid swizzle.
// EPI 0: lin = rstd*(acc - mu*S1) + bias, KAN+NCT, bf16 out (Ktot=6144
//        mapped: seg0 hi*hi, seg1 lo*hi, seg2 hi*lo — HALF path only).
// EPI 1: acc+bias, KAN+NCT, bf16.  EPI 2: acc+bias, f32.
// ============================================================================
template <int EPI>
__global__ __launch_bounds__(256, 2)
void gemm_kan2(const unsigned short* __restrict__ Ab,
               const unsigned short* __restrict__ Bb,
               const float* __restrict__ bias, const float* __restrict__ cp,
               const float* __restrict__ rw, const float* __restrict__ mu,
               const float* __restrict__ rstd, const float* __restrict__ S1,
               void* __restrict__ outp,
               int Nld, int n0, int Ktot, int lda, int ldb)
{
    constexpr int BM = 64, BN = 128, BK = 64;
    constexpr int ASZ = BM * BK;        // 4096 shorts = 8 KB
    constexpr int BUF = ASZ + BN * BK;  // 12288 shorts = 24 KB
    __shared__ unsigned short lds[3 * BUF];  // 72 KB triple buffer

    const int tid  = threadIdx.x;
    const int lane = tid & 63;
    const int wid  = tid >> 6;

    // XCD-chunked bijective swizzle (nwg % 8 == 0 for every launch here)
    const int gx = gridDim.x;
    int flat = blockIdx.y * gx + blockIdx.x;
    const int nwg = gx * gridDim.y;
    if ((nwg & 7) == 0) flat = (flat & 7) * (nwg >> 3) + (flat >> 3);
    const int bm = (flat % gx) * BM;
    const int bn = (flat / gx) * BN;

    const int wmo = (wid >> 1) * 32;   // wave row offset within BM
    const int wno = (wid & 1) * 64;    // wave col offset within BN
    const int fr = lane & 15;
    const int kq = lane >> 4;
    const int sxr = fr & 7;            // read-side XOR term (row & 7)

    // staging unit u: LDS linear dest = u*16B (row u>>3, 16B-slot u&7);
    // global source slot = (u&7) ^ (row&7)   [inverse swizzle on source]
    const int uA0 = (wid << 7) + lane;          // A: 512 units, 2 per thread
    const int uA1 = uA0 + 64;
    const int uB0 = (wid << 8) + lane;          // B: 1024 units, 4 per thread
    const int uB1 = uB0 + 64, uB2 = uB0 + 128, uB3 = uB0 + 192;
#define SRCOL(u) (((((u) & 7) ^ (((u) >> 3) & 7))) << 3)
    const size_t aoff0 = (size_t)(bm + (uA0 >> 3)) * lda + SRCOL(uA0);
    const size_t aoff1 = (size_t)(bm + (uA1 >> 3)) * lda + SRCOL(uA1);
    const size_t boff0 = (size_t)(bn + (uB0 >> 3)) * ldb + SRCOL(uB0);
    const size_t boff1 = (size_t)(bn + (uB1 >> 3)) * ldb + SRCOL(uB1);
    const size_t boff2 = (size_t)(bn + (uB2 >> 3)) * ldb + SRCOL(uB2);
    const size_t boff3 = (size_t)(bn + (uB3 >> 3)) * ldb + SRCOL(uB3);
#undef SRCOL

    f32x4 acc[2][4] = {};

#define STAGE(BSEL, AK, BKK) do {                                     \
    unsigned short* lA_ = &lds[(BSEL) * BUF];                         \
    unsigned short* lB_ = lA_ + ASZ;                                  \
    gl16(lA_ + uA0 * 8, Ab + aoff0 + (AK));                           \
    gl16(lA_ + uA1 * 8, Ab + aoff1 + (AK));                           \
    gl16(lB_ + uB0 * 8, Bb + boff0 + (BKK));                          \
    gl16(lB_ + uB1 * 8, Bb + boff1 + (BKK));                          \
    gl16(lB_ + uB2 * 8, Bb + boff2 + (BKK));                          \
    gl16(lB_ + uB3 * 8, Bb + boff3 + (BKK));                          \
} while (0)

    const int nt = Ktot / BK;
    STAGE(0, 0, 0);
    STAGE(1, BK, BK);   // kn=64 < 2048: no segment remap needed at any EPI

    for (int t = 0; t < nt; ++t) {
        // counted drain: allow the (t+1)-tile STAGE (6 loads) to stay in
        // flight across the barrier; own t-tile loads are then complete.
        if (t + 1 < nt) asm volatile("s_waitcnt vmcnt(6)" ::: "memory");
        else            asm volatile("s_waitcnt vmcnt(0)" ::: "memory");
        __builtin_amdgcn_s_barrier();
        __builtin_amdgcn_sched_barrier(0);  // pin ds_reads below the barrier
        if (t + 2 < nt) {
            const int kn = (t + 2) * BK;
            int ak = kn, bk = kn;
            if (EPI == 0) {
                ak = (kn < 4096) ? kn : kn - 4096;
                bk = (kn < 2048) ? kn : kn - 2048;
            }
            STAGE((t + 2) % 3, ak, bk);
        }
        const unsigned short* cl = &lds[(t % 3) * BUF];
#pragma unroll
        for (int s = 0; s < 2; ++s) {
            const int sl = ((((s << 2) + kq) ^ sxr)) << 3;  // swizzled 16B slot
            bf16x8 aF[2], bF[4];
#pragma unroll
            for (int i = 0; i < 2; ++i)
                aF[i] = *(const bf16x8*)&cl[(wmo + i * 16 + fr) * BK + sl];
#pragma unroll
            for (int j = 0; j < 4; ++j)
                bF[j] = *(const bf16x8*)&cl[ASZ + (wno + j * 16 + fr) * BK + sl];
#pragma unroll
            for (int i = 0; i < 2; ++i)
#pragma unroll
                for (int j = 0; j < 4; ++j)
                    acc[i][j] = __builtin_amdgcn_mfma_f32_16x16x32_bf16(aF[i], bF[j], acc[i][j], 0, 0, 0);
        }
    }
#undef STAGE

    // ---- epilogue: C layout col = lane&15, row = (lane>>4)*4 + reg ----
    const int rowg = (lane >> 4) * 4;
#pragma unroll
    for (int j = 0; j < 4; ++j) {
        const int n = n0 + bn + wno + j * 16 + fr;
        const float bs = bias[n];
        float cpf[8], rwf = 0.0f, s1 = 0.0f;
        if (EPI < 2) {
#pragma unroll
            for (int q = 0; q < 8; ++q) cpf[q] = cp[(size_t)n * 9 + q];
            rwf = rw[n];
        }
        if (EPI == 0) s1 = S1[n];
        const int s = n & 7;  // generator slot: {0,1}->sx, {2,3}->sy, {4..7}->identity
#pragma unroll
        for (int i = 0; i < 2; ++i) {
            const int m0 = bm + wmo + i * 16 + rowg;
#pragma unroll
            for (int r = 0; r < 4; ++r) {
                const int m = m0 + r;
                float v = acc[i][j][r];
                if (EPI == 0) v = (v - mu[m] * s1) * rstd[m] + bs;
                else          v += bs;
                if (EPI < 2) {
                    v = kan_spline(tanhf(v), cpf, rwf);
                    float p = __shfl_xor(v, 1, 64);  // partner col n^1 lives in lane^1
                    p = fminf(fmaxf(p, -1.0f), 1.0f);
                    if (s < 4) v += ((s == 2) ? -0.05f : 0.05f) * p;
                }
                if (EPI == 2) ((float*)outp)[(size_t)m * Nld + n] = v;
                else ((unsigned short*)outp)[(size_t)m * Nld + n] = f2b(v);
            }
        }
    }
}

// ============================================================================
// Legacy 64x64 kernel kept ONLY for the small-workspace insurance path
// (in-loop f32->bf16 conversion variants BSRC 1/2). Unchanged.
// ============================================================================
template <int EPI, int BSRC>
__global__ __launch_bounds__(256, 2)
void gemm_kan(const void* __restrict__ Av, const void* __restrict__ Bv,
              const float* __restrict__ bias, const float* __restrict__ cp,
              const float* __restrict__ rw, const float* __restrict__ mu,
              const float* __restrict__ rstd, const float* __restrict__ S1,
              void* __restrict__ outp,
              int Nld, int n0, int Ktot, int lda, int ldb)
{
    constexpr int BM = 64, BN = 64, BK = 64, LDP = 72;
    constexpr bool SPL = (BSRC == 2);
    constexpr int OFF_B  = BM * LDP;
    constexpr int OFF_LO = (BM + BN) * LDP;
    __shared__ unsigned short lds[(SPL ? 2 : 1) * (BM + BN) * LDP];

    const int tid  = threadIdx.x;
    const int lane = tid & 63;
    const int wid  = tid >> 6;
    const int bm = blockIdx.x * BM;
    const int bn = blockIdx.y * BN;
    const int wmo = (wid >> 1) * 32;
    const int wno = (wid & 1) * 32;
    const int fr = lane & 15;
    const int kq = lane >> 4;
    const int sar = tid >> 3, sac = (tid & 7) << 3;
    const int sfr = tid >> 2, sfc = (tid & 3) << 4;

    f32x4 acc[2][2] = {};

    uint4 pA0 = {}, pA1 = {}, pB0 = {}, pB1 = {};
    const unsigned short* Ab = (const unsigned short*)Av;
    const unsigned short* Bb = (const unsigned short*)Bv;
    const size_t a0 = (size_t)(bm + sar) * lda + sac;
    const size_t a1 = (size_t)(bm + 32 + sar) * lda + sac;
    const size_t b0 = (size_t)(bn + sar) * ldb + sac;
    const size_t b1 = (size_t)(bn + 32 + sar) * ldb + sac;
    if constexpr (BSRC == 0) {
        pA0 = *(const uint4*)(Ab + a0);
        pA1 = *(const uint4*)(Ab + a1);
        pB0 = *(const uint4*)(Bb + b0);
        pB1 = *(const uint4*)(Bb + b1);
    }

    for (int k0 = 0; k0 < Ktot; k0 += BK) {
        if constexpr (BSRC == 0) {
            *(uint4*)&lds[sar * LDP + sac] = pA0;
            *(uint4*)&lds[(32 + sar) * LDP + sac] = pA1;
            *(uint4*)&lds[OFF_B + sar * LDP + sac] = pB0;
            *(uint4*)&lds[OFF_B + (32 + sar) * LDP + sac] = pB1;
        } else {
            {
                const float* g = (const float*)Bv + (size_t)(bn + sfr) * ldb + k0 + sfc;
                float4 u0 = ((const float4*)g)[0];
                float4 u1 = ((const float4*)g)[1];
                float4 u2 = ((const float4*)g)[2];
                float4 u3 = ((const float4*)g)[3];
                float v[16] = {u0.x,u0.y,u0.z,u0.w, u1.x,u1.y,u1.z,u1.w,
                               u2.x,u2.y,u2.z,u2.w, u3.x,u3.y,u3.z,u3.w};
                unsigned short hi[16], lo[16];
#pragma unroll
                for (int i = 0; i < 16; ++i) {
                    hi[i] = f2b(v[i]);
                    if (SPL) lo[i] = f2b(v[i] - b2f(hi[i]));
                }
                unsigned short* d = &lds[OFF_B + sfr * LDP + sfc];
                ((uint4*)d)[0] = *(const uint4*)&hi[0];
                ((uint4*)d)[1] = *(const uint4*)&hi[8];
                if constexpr (SPL) {
                    unsigned short* dl = d + OFF_LO;
                    ((uint4*)dl)[0] = *(const uint4*)&lo[0];
                    ((uint4*)dl)[1] = *(const uint4*)&lo[8];
                }
            }
            if constexpr (SPL) {
                const float* g = (const float*)Av + (size_t)(bm + sfr) * lda + k0 + sfc;
                float4 u0 = ((const float4*)g)[0];
                float4 u1 = ((const float4*)g)[1];
                float4 u2 = ((const float4*)g)[2];
                float4 u3 = ((const float4*)g)[3];
                float v[16] = {u0.x,u0.y,u0.z,u0.w, u1.x,u1.y,u1.z,u1.w,
                               u2.x,u2.y,u2.z,u2.w, u3.x,u3.y,u3.z,u3.w};
                unsigned short hi[16], lo[16];
#pragma unroll
                for (int i = 0; i < 16; ++i) {
                    hi[i] = f2b(v[i]);
                    lo[i] = f2b(v[i] - b2f(hi[i]));
                }
                unsigned short* d = &lds[sfr * LDP + sfc];
                ((uint4*)d)[0] = *(const uint4*)&hi[0];
                ((uint4*)d)[1] = *(const uint4*)&hi[8];
                unsigned short* dl = d + OFF_LO;
                ((uint4*)dl)[0] = *(const uint4*)&lo[0];
                ((uint4*)dl)[1] = *(const uint4*)&lo[8];
            } else {
                *(uint4*)&lds[sar * LDP + sac] = *(const uint4*)(Ab + a0 + k0);
                *(uint4*)&lds[(32 + sar) * LDP + sac] = *(const uint4*)(Ab + a1 + k0);
            }
        }
        __syncthreads();
        if constexpr (BSRC == 0) {
            if (k0 + BK < Ktot) {
                const int kn = k0 + BK;
                const int ak = (EPI == 0) ? (kn < 4096 ? kn : kn - 4096) : kn;
                const int bk = (EPI == 0) ? (kn < 2048 ? kn : kn - 2048) : kn;
                pA0 = *(const uint4*)(Ab + a0 + ak);
                pA1 = *(const uint4*)(Ab + a1 + ak);
                pB0 = *(const uint4*)(Bb + b0 + bk);
                pB1 = *(const uint4*)(Bb + b1 + bk);
            }
        }
#pragma unroll
        for (int s = 0; s < 2; ++s) {
            const int cc = (s * 4 + kq) << 3;
            bf16x8 aF[2], bF[2];
#pragma unroll
            for (int i = 0; i < 2; ++i)
                aF[i] = *(const bf16x8*)&lds[(wmo + i * 16 + fr) * LDP + cc];
#pragma unroll
            for (int j = 0; j < 2; ++j)
                bF[j] = *(const bf16x8*)&lds[OFF_B + (wno + j * 16 + fr) * LDP + cc];
#pragma unroll
            for (int i = 0; i < 2; ++i)
#pragma unroll
                for (int j = 0; j < 2; ++j)
                    acc[i][j] = __builtin_amdgcn_mfma_f32_16x16x32_bf16(aF[i], bF[j], acc[i][j], 0, 0, 0);
            if constexpr (SPL) {
                bf16x8 aL[2], bL[2];
#pragma unroll
                for (int i = 0; i < 2; ++i)
                    aL[i] = *(const bf16x8*)&lds[OFF_LO + (wmo + i * 16 + fr) * LDP + cc];
#pragma unroll
                for (int i = 0; i < 2; ++i)
#pragma unroll
                    for (int j = 0; j < 2; ++j)
                        acc[i][j] = __builtin_amdgcn_mfma_f32_16x16x32_bf16(aL[i], bF[j], acc[i][j], 0, 0, 0);
#pragma unroll
                for (int j = 0; j < 2; ++j)
                    bL[j] = *(const bf16x8*)&lds[OFF_LO + OFF_B + (wno + j * 16 + fr) * LDP + cc];
#pragma unroll
                for (int i = 0; i < 2; ++i)
#pragma unroll
                    for (int j = 0; j < 2; ++j)
                        acc[i][j] = __builtin_amdgcn_mfma_f32_16x16x32_bf16(aF[i], bL[j], acc[i][j], 0, 0, 0);
            }
        }
        __syncthreads();
    }

    const int rowg = (lane >> 4) * 4;
#pragma unroll
    for (int j = 0; j < 2; ++j) {
        const int n = n0 + bn + wno + j * 16 + fr;
        const float bs = bias[n];
        float cpf[8], rwf = 0.0f, s1 = 0.0f;
        if (EPI < 2) {
#pragma unroll
            for (int q = 0; q < 8; ++q) cpf[q] = cp[(size_t)n * 9 + q];
            rwf = rw[n];
        }
        if (EPI == 0) s1 = S1[n];
        const int s = n & 7;
#pragma unroll
        for (int i = 0; i < 2; ++i) {
            const int m0 = bm + wmo + i * 16 + rowg;
#pragma unroll
            for (int r = 0; r < 4; ++r) {
                const int m = m0 + r;
                float v = acc[i][j][r];
                if (EPI == 0) v = (v - mu[m] * s1) * rstd[m] + bs;
                else          v += bs;
                if (EPI < 2) {
                    v = kan_spline(tanhf(v), cpf, rwf);
                    float p = __shfl_xor(v, 1, 64);
                    p = fminf(fmaxf(p, -1.0f), 1.0f);
                    if (s < 4) v += ((s == 2) ? -0.05f : 0.05f) * p;
                }
                if (EPI == 2) ((float*)outp)[(size_t)m * Nld + n] = v;
                else ((unsigned short*)outp)[(size_t)m * Nld + n] = f2b(v);
            }
        }
    }
}

extern "C" void kernel_launch(void* const* d_in, const int* in_sizes, int n_in,
                              void* d_out, int out_size, void* d_ws, size_t ws_size,
                              hipStream_t stream) {
    const float* x    = (const float*)d_in[0];
    const float* W1   = (const float*)d_in[1];
    const float* b1   = (const float*)d_in[2];
    const float* cp1  = (const float*)d_in[3];
    const float* rw1  = (const float*)d_in[4];
    const float* W2   = (const float*)d_in[5];
    const float* b2   = (const float*)d_in[6];
    const float* cp2  = (const float*)d_in[7];
    const float* rw2  = (const float*)d_in[8];
    const float* W3   = (const float*)d_in[9];
    const float* b3   = (const float*)d_in[10];
    const float* cp3  = (const float*)d_in[11];
    const float* rw3  = (const float*)d_in[12];
    const float* Wout = (const float*)d_in[13];
    const float* bout = (const float*)d_in[14];

    char* ws = (char*)d_ws;
    float* mu   = (float*)(ws);                  // 1024 f32
    float* rstd = (float*)(ws + 4096);           // 1024 f32
    float* S1   = (float*)(ws + 8192);           // 4096 f32
    unsigned short* A2 = (unsigned short*)(ws + 32768);              // 1024x4096 bf16 (8MB)
    unsigned short* A3 = (unsigned short*)(ws + 32768 + 8388608);    // 1024x4096 bf16 (8MB)
    unsigned short* A4 = A2;                      // A2 dead after L2 gemm
    unsigned short* Asplit = A3;                  // x split lives in A3 slot until L2 writes it
    unsigned short* Wb = (unsigned short*)(ws + 32768 + 2 * 8388608); // 32MB region
    const size_t NEED_FULL = 32768 + 2 * 8388608 + 33554432;  // 50.4 MB
    const size_t NEED_HALF = 32768 + 2 * 8388608 + 16777216;  // 33.6 MB

    if (ws_size >= NEED_FULL) {
        // 7 launches (round-7 structure; L1 uses the fused hi/lo kernel).
        pre_all<<<5120, 256, 0, stream>>>(x, W1, mu, rstd, S1, Asplit, Wb);
        gemm_kan1<<<dim3(16, 32), 256, 0, stream>>>(
            Asplit, Wb, b1, cp1, rw1, mu, rstd, S1, A2, 4096, 2048, 4096, 4096);
        cvt_kernel<<<8192, 256, 0, stream>>>(W2, Wb);
        gemm_kan2<1><<<dim3(16, 32), 256, 0, stream>>>(
            A2, Wb, b2, cp2, rw2, nullptr, nullptr, nullptr, A3, 4096, 0, 4096, 4096, 4096);
        cvt2_kernel<<<6144, 256, 0, stream>>>(W3, Wb, 4096, Wout, Wb + 8388608);
        gemm_kan2<1><<<dim3(16, 16), 256, 0, stream>>>(
            A3, Wb, b3, cp3, rw3, nullptr, nullptr, nullptr, A4, 2048, 0, 4096, 4096, 4096);
        gemm_kan2<2><<<dim3(16, 16), 256, 0, stream>>>(
            A4, Wb + 8388608, bout, nullptr, nullptr, nullptr, nullptr, nullptr, d_out, 2048, 0, 2048, 2048, 2048);
    } else if (ws_size >= NEED_HALF) {
        ln_stats_kernel<<<1024, 256, 0, stream>>>(x, mu, rstd);
        rowsum_kernel<<<1024, 256, 0, stream>>>(W1, S1, 2048);
        split2_kernel<<<1024, 256, 0, stream>>>(x, Asplit, 2048);
        for (int h = 0; h < 2; ++h) {
            split2_kernel<<<2048, 256, 0, stream>>>(W1 + (size_t)h * 2048 * 2048, Wb, 2048);
            gemm_kan2<0><<<dim3(16, 16), 256, 0, stream>>>(
                Asplit, Wb, b1, cp1, rw1, mu, rstd, S1, A2, 4096, h * 2048, 6144, 4096, 4096);
        }
        for (int h = 0; h < 2; ++h) {
            cvt_kernel<<<4096, 256, 0, stream>>>(W2 + (size_t)h * 2048 * 4096, Wb);
            gemm_kan2<1><<<dim3(16, 16), 256, 0, stream>>>(
                A2, Wb, b2, cp2, rw2, nullptr, nullptr, nullptr, A3, 4096, h * 2048, 4096, 4096, 4096);
        }
        cvt_kernel<<<4096, 256, 0, stream>>>(W3, Wb);
        gemm_kan2<1><<<dim3(16, 16), 256, 0, stream>>>(
            A3, Wb, b3, cp3, rw3, nullptr, nullptr, nullptr, A4, 2048, 0, 4096, 4096, 4096);
        cvt_kernel<<<2048, 256, 0, stream>>>(Wout, Wb);
        gemm_kan2<2><<<dim3(16, 16), 256, 0, stream>>>(
            A4, Wb, bout, nullptr, nullptr, nullptr, nullptr, nullptr, d_out, 2048, 0, 2048, 2048, 2048);
    } else {
        // 16.8 MB insurance path: in-loop conversion (round-4-proven staging)
        ln_stats_kernel<<<1024, 256, 0, stream>>>(x, mu, rstd);
        rowsum_kernel<<<1024, 256, 0, stream>>>(W1, S1, 2048);
        gemm_kan<0, 2><<<dim3(16, 64), 256, 0, stream>>>(
            x, W1, b1, cp1, rw1, mu, rstd, S1, A2, 4096, 0, 2048, 2048, 2048);
        gemm_kan<1, 1><<<dim3(16, 64), 256, 0, stream>>>(
            A2, W2, b2, cp2, rw2, nullptr, nullptr, nullptr, A3, 4096, 0, 4096, 4096, 4096);
        gemm_kan<1, 1><<<dim3(16, 32), 256, 0, stream>>>(
            A3, W3, b3, cp3, rw3, nullptr, nullptr, nullptr, A4, 2048, 0, 4096, 4096, 4096);
        gemm_kan<2, 1><<<dim3(16, 32), 256, 0, stream>>>(
            A4, Wout, bout, nullptr, nullptr, nullptr, nullptr, nullptr, d_out, 2048, 0, 2048, 2048, 2048);
    }
}